// Round 10
// baseline (1733.314 us; speedup 1.0000x reference)
//
#include <hip/hip_runtime.h>
#include <stdint.h>

// Fused linear -> logsumexp -> NLL(sum), TOKENS x DMODEL @ (VOCAB x DMODEL)^T.
// Round 10: hybrid A-in-reg + B-in-LDS with counted-vmcnt single-barrier loop.
//  - A fragments global->VGPR (frag-major ws; L2-resident 1MB/XCD), ping-pong
//    1 kstep ahead: a(k) in aA for even k, aB for odd k. No A LDS traffic.
//  - B triple-buffered LDS (3x16KB), staged 2 ksteps ahead via global_load_lds;
//    ONE raw s_barrier + s_waitcnt vmcnt(6) per kstep (never 0 in main loop).
//    Safety: barrier at iter k fences readers of buf[(k+2)%3] (last read k-1);
//    vmcnt(6) leaves exactly B(k+1)+a(k+1) in flight => B(k) landed.
//  - __launch_bounds__(256,2): unified <=256 regs (need ~222) => 2 waves/SIMD.
//    (r7: cap 170 => spill disaster; r9: no cap => ~288 regs => 1 wave/SIMD.)
//  - Identity frag-major layouts (r7: read-side swizzle measured null).

#define TOKENS 8192
#define DMODEL 1024
#define VOCAB  32000

#define NBMF   (TOKENS / 128)   // 64
#define NBNF   (VOCAB / 256)    // 125
#define NWGF   (NBMF * NBNF)    // 8000 = 8 bands x 1000

#define NBM    (TOKENS / 128)
#define NBN    (VOCAB / 128)
#define NWG    (NBM * NBN)
#define CHUNK  (NWG / 8)

typedef float  f32x4   __attribute__((ext_vector_type(4)));
typedef float  f32x16  __attribute__((ext_vector_type(16)));
typedef int    i32x8   __attribute__((ext_vector_type(8)));
typedef __bf16 bf16x8  __attribute__((ext_vector_type(8)));
typedef unsigned short u16;
typedef u16 u16x4 __attribute__((ext_vector_type(4)));

__device__ __forceinline__ u16 f2bf(float f) {
  union { float f; uint32_t u; } v; v.f = f;
  return (u16)((v.u + 0x7FFFu + ((v.u >> 16) & 1u)) >> 16);
}

__device__ __forceinline__ uint8_t f2e4m3(float x) {
  union { float f; uint32_t u; } v; v.f = x;
  const uint32_t s = (v.u >> 24) & 0x80u;
  const float ax = fabsf(x);
  if (ax >= 464.f) return (uint8_t)(s | 0x7E);
  if (ax < 0.015625f) {
    const int q = (int)rintf(ax * 512.f);
    return (uint8_t)(s | (uint32_t)q);
  }
  uint32_t u = v.u;
  u += 0x000FFFFFu + ((u >> 20) & 1u);
  const int E = (int)((u >> 23) & 0xFF) - 127;
  const uint32_t m3 = (u >> 20) & 0x7u;
  return (uint8_t)(s | (uint32_t)(((E + 7) << 3) | m3));
}

__device__ __forceinline__ void g2lds16(const void* gsrc, void* ldst) {
  __builtin_amdgcn_global_load_lds(
      (const __attribute__((address_space(1))) uint32_t*)(uintptr_t)gsrc,
      (__attribute__((address_space(3))) uint32_t*)(uintptr_t)ldst,
      16, 0, 0);
}

__device__ __forceinline__ void bar() {
  asm volatile("" ::: "memory");
  __builtin_amdgcn_s_barrier();
  asm volatile("" ::: "memory");
}
__device__ __forceinline__ void vm6() {
  asm volatile("s_waitcnt vmcnt(6)" ::: "memory");
}

// fp32 -> fp8, identity frag-major tiled layout (see r9/r10 notes).
__global__ void convert_fp8_tiled(const float* __restrict__ in, uint8_t* __restrict__ out,
                                  long long total, int log2ts, float scale) {
  const long long step = (long long)gridDim.x * blockDim.x * 8;
  const int NR = 1 << (log2ts - 6);
  for (long long d = ((long long)blockIdx.x * blockDim.x + threadIdx.x) * 8;
       d < total; d += step) {
    const long long tile = d >> log2ts;
    const int x   = (int)(d & ((1LL << log2ts) - 1));
    const int sub = x >> 11;
    const int rem = x & 2047;
    const int l   = rem >> 5;
    const int rb  = (int)(tile >> 4);
    const int kt  = (int)(tile & 15);
    const int row = rb * NR + sub * 32 + (l & 31);
    const int k   = kt * 64 + (l >> 5) * 32 + (rem & 31);
    const float* src = in + (size_t)row * DMODEL + k;
    const float4 f0 = *(const float4*)src;
    const float4 f1 = *(const float4*)(src + 4);
    uint8_t r[8] = { f2e4m3(f0.x * scale), f2e4m3(f0.y * scale),
                     f2e4m3(f0.z * scale), f2e4m3(f0.w * scale),
                     f2e4m3(f1.x * scale), f2e4m3(f1.y * scale),
                     f2e4m3(f1.z * scale), f2e4m3(f1.w * scale) };
    *(uint64_t*)(out + d) = *(const uint64_t*)r;
  }
}

// ---------------- hybrid MX-fp8 fused GEMM + exp-row-sum ----------------
__global__ __launch_bounds__(256, 2)
void gemm_lse_fp8v5(const uint8_t* __restrict__ A8, const uint8_t* __restrict__ B8,
                    float* __restrict__ S) {
  __shared__ uint8_t Bs[3][16384];       // 48 KiB triple buffer (B only)

  const int lane = threadIdx.x & 63;
  const int wave = threadIdx.x >> 6;
  const int wr = wave >> 1, wc = wave & 1;

  const int lid  = blockIdx.x;
  const int band = lid & 7;
  const int idx2 = lid >> 3;
  const int bn   = idx2 >> 3;
  const int bm   = band * 8 + (idx2 & 7);
  const int arow = bm * 128;

  const uint8_t* Abase = A8 + (size_t)(bm * 16) * 8192 + (wr * 2) * 2048 + lane * 32;
  const uint8_t* Bsrc  = B8 + (size_t)(bn * 16) * 16384;

  f32x16 acc[2][4];
#pragma unroll
  for (int mi = 0; mi < 2; ++mi)
#pragma unroll
    for (int ni = 0; ni < 4; ++ni) acc[mi][ni] = (f32x16)(0.f);

  i32x8 aA[2], aB[2];

#define STAGE_B(buf, t)                                                     \
  _Pragma("unroll")                                                         \
  for (int p = 0; p < 4; ++p) {                                             \
    const int c = p * 4 + wave;                                             \
    g2lds16(Bsrc + (size_t)(t) * 16384 + c * 1024 + lane * 16,              \
            (void*)(&Bs[buf][c * 1024]));                                   \
  }
#define LOAD_A(dst, t)                                                      \
  _Pragma("unroll")                                                         \
  for (int mi = 0; mi < 2; ++mi)                                            \
    dst[mi] = *(const i32x8*)(Abase + (size_t)(t) * 8192 + mi * 2048);

  STAGE_B(0, 0)
  STAGE_B(1, 1)
  LOAD_A(aA, 0)
  vm6();
  bar();

#pragma unroll
  for (int k = 0; k < 16; ++k) {
    if (k < 14) { STAGE_B((k + 2) % 3, k + 2) }
    if (k < 15) {
      if (k & 1) { LOAD_A(aA, k + 1) } else { LOAD_A(aB, k + 1) }
    }
    if (k > 0) {
      vm6();
      bar();
    }
    {
      const uint8_t* bp = &Bs[k % 3][(wc * 4) * 2048 + lane * 32];
      i32x8 b[4];
#pragma unroll
      for (int ni = 0; ni < 4; ++ni) b[ni] = *(const i32x8*)(bp + ni * 2048);
      __builtin_amdgcn_s_setprio(1);
#pragma unroll
      for (int mi = 0; mi < 2; ++mi) {
#pragma unroll
        for (int ni = 0; ni < 4; ++ni)
          acc[mi][ni] = __builtin_amdgcn_mfma_scale_f32_32x32x64_f8f6f4(
              (k & 1) ? aB[mi] : aA[mi], b[ni], acc[mi][ni], 0, 0,
              0, 0x7F7F7F7F, 0, 0x7F7F7F7F);
      }
      __builtin_amdgcn_s_setprio(0);
    }
  }
#undef STAGE_B
#undef LOAD_A

#pragma unroll
  for (int mi = 0; mi < 2; ++mi) {
#pragma unroll
    for (int r = 0; r < 16; ++r) {
      float v = 0.f;
#pragma unroll
      for (int ni = 0; ni < 4; ++ni) v += __expf(acc[mi][ni][r] * 0.0625f);
      v += __shfl_xor(v, 1);
      v += __shfl_xor(v, 2);
      v += __shfl_xor(v, 4);
      v += __shfl_xor(v, 8);
      v += __shfl_xor(v, 16);
      if ((lane & 31) == 0) {
        const int row = arow + wr * 64 + mi * 32 + (r & 3) + 8 * (r >> 2) + 4 * (lane >> 5);
        atomicAdd(&S[row], v);
      }
    }
  }
}

// ---------------- 128^2 fp32 fallback (ws too small), unchanged ----------------
__global__ __launch_bounds__(256)
void gemm_lse_fb(const float* __restrict__ Af, const float* __restrict__ Bf,
                 float* __restrict__ S) {
  __shared__ u16 As[128 * 64];
  __shared__ u16 Bs[128 * 64];

  const int tid  = threadIdx.x;
  const int lane = tid & 63;
  const int wave = tid >> 6;
  const int wr = wave >> 1, wc = wave & 1;
  const int l15 = lane & 15, l4 = lane >> 4;

  const int lid = blockIdx.x;
  const int wid = (lid & 7) * CHUNK + (lid >> 3);
  const int bm = wid & (NBM - 1);
  const int bn = wid / NBM;

  f32x4 acc[4][4];
#pragma unroll
  for (int m = 0; m < 4; ++m)
#pragma unroll
    for (int n = 0; n < 4; ++n) acc[m][n] = (f32x4)(0.f);

  for (int kt = 0; kt < DMODEL / 64; ++kt) {
    const int k0 = kt * 64;
    {
      const int row = tid >> 4;
      const int kq  = (tid & 15) * 4;
#pragma unroll
      for (int r = 0; r < 8; ++r) {
        const int rr = r * 16 + row;
        const int kd = kq ^ ((rr & 7) << 3);
        float4 a4 = *(const float4*)(Af + (size_t)(bm * 128 + rr) * DMODEL + k0 + kq);
        float4 b4 = *(const float4*)(Bf + (size_t)(bn * 128 + rr) * DMODEL + k0 + kq);
        u16x4 ap = { f2bf(a4.x), f2bf(a4.y), f2bf(a4.z), f2bf(a4.w) };
        u16x4 bp = { f2bf(b4.x), f2bf(b4.y), f2bf(b4.z), f2bf(b4.w) };
        *(u16x4*)&As[rr * 64 + kd] = ap;
        *(u16x4*)&Bs[rr * 64 + kd] = bp;
      }
    }
    __syncthreads();
#pragma unroll
    for (int kk = 0; kk < 2; ++kk) {
      bf16x8 av[4], bv[4];
      const int swz = (l15 & 7) << 3;
      const int kc  = (kk * 32 + l4 * 8) ^ swz;
#pragma unroll
      for (int m = 0; m < 4; ++m)
        av[m] = *(const bf16x8*)&As[(wr * 64 + m * 16 + l15) * 64 + kc];
#pragma unroll
      for (int n = 0; n < 4; ++n)
        bv[n] = *(const bf16x8*)&Bs[(wc * 64 + n * 16 + l15) * 64 + kc];
#pragma unroll
      for (int m = 0; m < 4; ++m)
#pragma unroll
        for (int n = 0; n < 4; ++n)
          acc[m][n] = __builtin_amdgcn_mfma_f32_16x16x32_bf16(av[m], bv[n], acc[m][n], 0, 0, 0);
    }
    __syncthreads();
  }

#pragma unroll
  for (int m = 0; m < 4; ++m) {
#pragma unroll
    for (int j = 0; j < 4; ++j) {
      float v = 0.f;
#pragma unroll
      for (int n = 0; n < 4; ++n) v += __expf(acc[m][n][j]);
      v += __shfl_xor(v, 1);
      v += __shfl_xor(v, 2);
      v += __shfl_xor(v, 4);
      v += __shfl_xor(v, 8);
      if (l15 == 0) {
        const int row = bm * 128 + wr * 64 + m * 16 + l4 * 4 + j;
        atomicAdd(&S[row], v);
      }
    }
  }
}

// ---------------- exact fp32 target score ----------------
__global__ void target_score_k(const float* __restrict__ inp, const float* __restrict__ W,
                               const int* __restrict__ tgt, float* __restrict__ ts) {
  const int gtid = blockIdx.x * blockDim.x + threadIdx.x;
  const int t = gtid >> 6;
  const int lane = threadIdx.x & 63;
  if (t >= TOKENS) return;
  bool allhi0 = true, anylo = false;
  for (int i = 0; i < 64; ++i) {
    if (tgt[2 * i + 1] != 0) allhi0 = false;
    if (tgt[2 * i] != 0) anylo = true;
  }
  const int v = (allhi0 && anylo) ? tgt[2 * t] : tgt[t];
  const float4* xr = (const float4*)(inp + (size_t)t * DMODEL);
  const float4* wr = (const float4*)(W + (size_t)v * DMODEL);
  float s = 0.f;
#pragma unroll
  for (int i = 0; i < 4; ++i) {
    float4 a = xr[lane + 64 * i];
    float4 b = wr[lane + 64 * i];
    s += a.x * b.x + a.y * b.y + a.z * b.z + a.w * b.w;
  }
#pragma unroll
  for (int off = 32; off >= 1; off >>= 1) s += __shfl_xor(s, off);
  if (lane == 0) ts[t] = s;
}

__global__ void finalize_k(const float* __restrict__ S, const float* __restrict__ ts,
                           float* __restrict__ out) {
  __shared__ float red[16];
  float s = 0.f;
  for (int t = threadIdx.x; t < TOKENS; t += blockDim.x) s += __logf(S[t]) - ts[t];
#pragma unroll
  for (int off = 32; off >= 1; off >>= 1) s += __shfl_xor(s, off);
  const int wave = threadIdx.x >> 6, lane = threadIdx.x & 63;
  if (lane == 0) red[wave] = s;
  __syncthreads();
  if (threadIdx.x == 0) {
    float tot = 0.f;
    for (int w = 0; w < (int)(blockDim.x >> 6); ++w) tot += red[w];
    out[0] = tot;
  }
}

extern "C" void kernel_launch(void* const* d_in, const int* in_sizes, int n_in,
                              void* d_out, int out_size, void* d_ws, size_t ws_size,
                              hipStream_t stream) {
  const float* inp = (const float*)d_in[0];
  const float* W   = (const float*)d_in[1];
  const int*   tgt = (const int*)d_in[2];
  float* out = (float*)d_out;

  char* ws = (char*)d_ws;
  float* S  = (float*)ws;
  float* ts = (float*)(ws + 32 * 1024);
  const size_t offA = 64 * 1024;
  const long long totalA = (long long)TOKENS * DMODEL;
  const long long totalB = (long long)VOCAB * DMODEL;
  const size_t offB = offA + (size_t)totalA;
  const size_t need = offB + (size_t)totalB;             // ~41.2 MB
  const bool preconv = ws_size >= need;

  hipMemsetAsync(S, 0, TOKENS * sizeof(float), stream);

  if (preconv) {
    uint8_t* A8 = (uint8_t*)(ws + offA);
    uint8_t* B8 = (uint8_t*)(ws + offB);
    convert_fp8_tiled<<<4096, 256, 0, stream>>>(inp, A8, totalA, 13, 1.0f);
    convert_fp8_tiled<<<16000, 256, 0, stream>>>(W, B8, totalB, 14, 16.0f);
    gemm_lse_fp8v5<<<NWGF, 256, 0, stream>>>(A8, B8, S);
  } else {
    gemm_lse_fb<<<NWG, 256, 0, stream>>>(inp, W, S);
  }
  target_score_k<<<(TOKENS * 64) / 256, 256, 0, stream>>>(inp, W, tgt, ts);
  finalize_k<<<1, 1024, 0, stream>>>(S, ts, out);
}

// Round 11
// 1162.148 us; speedup vs baseline: 1.4915x; 1.4915x over previous
//
#include <hip/hip_runtime.h>
#include <stdint.h>

// Fused linear -> logsumexp -> NLL(sum), TOKENS x DMODEL @ (VOCAB x DMODEL)^T.
// Round 11: r6's register profile (no persistent operand regs, NO launch_bounds
// min-waves -- r7/r10 both spilled catastrophically with it) + counted-vmcnt
// 2-deep LDS pipeline:
//  - A+B triple-buffered in LDS (3 x 24KB = 72KB => 2 blocks/CU).
//  - Per kstep: stage(k+2) -> compute(k) -> vmcnt(6)+s_barrier.
//    vmcnt(6) leaves only stage(k+2) (6 loads/thread) in flight => stage(k+1)
//    landed; barrier makes it cooperative. Drain covers ~2 compute phases.
//  - Race-free: stage(k+2) overwrites buf[(k-1)%3]; its readers all passed
//    the previous end-of-iter barrier (verified pattern from r4).
//  - Identity frag-major workspace layout (r7: read swizzle = null).

#define TOKENS 8192
#define DMODEL 1024
#define VOCAB  32000

// fp8 geometry: block 128x256, 4 waves (2x2), wave tile 64x128
#define NBMF   (TOKENS / 128)   // 64
#define NBNF   (VOCAB / 256)    // 125
#define NWGF   (NBMF * NBNF)    // 8000 = 8 bands x 1000

// fp32 fallback geometry
#define NBM    (TOKENS / 128)
#define NBN    (VOCAB / 128)
#define NWG    (NBM * NBN)
#define CHUNK  (NWG / 8)

typedef float  f32x4   __attribute__((ext_vector_type(4)));
typedef float  f32x16  __attribute__((ext_vector_type(16)));
typedef int    i32x8   __attribute__((ext_vector_type(8)));
typedef __bf16 bf16x8  __attribute__((ext_vector_type(8)));
typedef unsigned short u16;
typedef u16 u16x4 __attribute__((ext_vector_type(4)));

__device__ __forceinline__ u16 f2bf(float f) {
  union { float f; uint32_t u; } v; v.f = f;
  return (u16)((v.u + 0x7FFFu + ((v.u >> 16) & 1u)) >> 16);
}

// fp32 -> OCP e4m3fn, RNE, saturating.
__device__ __forceinline__ uint8_t f2e4m3(float x) {
  union { float f; uint32_t u; } v; v.f = x;
  const uint32_t s = (v.u >> 24) & 0x80u;
  const float ax = fabsf(x);
  if (ax >= 464.f) return (uint8_t)(s | 0x7E);
  if (ax < 0.015625f) {
    const int q = (int)rintf(ax * 512.f);
    return (uint8_t)(s | (uint32_t)q);
  }
  uint32_t u = v.u;
  u += 0x000FFFFFu + ((u >> 20) & 1u);
  const int E = (int)((u >> 23) & 0xFF) - 127;
  const uint32_t m3 = (u >> 20) & 0x7u;
  return (uint8_t)(s | (uint32_t)(((E + 7) << 3) | m3));
}

__device__ __forceinline__ void g2lds16(const void* gsrc, void* ldst) {
  __builtin_amdgcn_global_load_lds(
      (const __attribute__((address_space(1))) uint32_t*)(uintptr_t)gsrc,
      (__attribute__((address_space(3))) uint32_t*)(uintptr_t)ldst,
      16, 0, 0);
}

__device__ __forceinline__ void bar() {
  asm volatile("" ::: "memory");
  __builtin_amdgcn_s_barrier();
  asm volatile("" ::: "memory");
}
template <int N> __device__ __forceinline__ void vmw() {
  if constexpr (N == 6)      asm volatile("s_waitcnt vmcnt(6)" ::: "memory");
  else if constexpr (N == 0) asm volatile("s_waitcnt vmcnt(0)" ::: "memory");
}

// fp32 -> fp8, identity frag-major tiled layout.
// Tile = (row-block rb of NR=2^(log2ts-6) rows) x (kstep kt of 64 k),
// frag regions of 2048B (32 rows x 64 k). Byte x in tile:
//   sub=x>>11; l=(x&2047)>>5; row=rb*NR+sub*32+(l&31); k=kt*64+(l>>5)*32+(x&31).
__global__ void convert_fp8_tiled(const float* __restrict__ in, uint8_t* __restrict__ out,
                                  long long total, int log2ts, float scale) {
  const long long step = (long long)gridDim.x * blockDim.x * 8;
  const int NR = 1 << (log2ts - 6);
  for (long long d = ((long long)blockIdx.x * blockDim.x + threadIdx.x) * 8;
       d < total; d += step) {
    const long long tile = d >> log2ts;
    const int x   = (int)(d & ((1LL << log2ts) - 1));
    const int sub = x >> 11;
    const int rem = x & 2047;
    const int l   = rem >> 5;
    const int rb  = (int)(tile >> 4);
    const int kt  = (int)(tile & 15);
    const int row = rb * NR + sub * 32 + (l & 31);
    const int k   = kt * 64 + (l >> 5) * 32 + (rem & 31);
    const float* src = in + (size_t)row * DMODEL + k;
    const float4 f0 = *(const float4*)src;
    const float4 f1 = *(const float4*)(src + 4);
    uint8_t r[8] = { f2e4m3(f0.x * scale), f2e4m3(f0.y * scale),
                     f2e4m3(f0.z * scale), f2e4m3(f0.w * scale),
                     f2e4m3(f1.x * scale), f2e4m3(f1.y * scale),
                     f2e4m3(f1.z * scale), f2e4m3(f1.w * scale) };
    *(uint64_t*)(out + d) = *(const uint64_t*)r;
  }
}

// ---------------- MX-fp8 fused GEMM + exp-row-sum, 2-deep pipeline ----------------
__global__ __launch_bounds__(256)
void gemm_lse_fp8v6(const uint8_t* __restrict__ A8, const uint8_t* __restrict__ B8,
                    float* __restrict__ S) {
  __shared__ uint8_t smem[3][24576];     // 72 KiB: per buf, A 8K | B 16K

  const int lane = threadIdx.x & 63;
  const int wave = threadIdx.x >> 6;         // 0..3
  const int wr = wave >> 1, wc = wave & 1;   // 2x2; wave tile 64x128

  // Supertile XCD map: band owns bm in [band*8, band*8+8), bn-major sweep.
  const int lid  = blockIdx.x;
  const int band = lid & 7;
  const int idx2 = lid >> 3;                 // 0..999
  const int bn   = idx2 >> 3;                // 0..124
  const int bm   = band * 8 + (idx2 & 7);    // 0..63
  const int arow = bm * 128;

  const uint8_t* Asrc = A8 + (size_t)(bm * 16) * 8192;
  const uint8_t* Bsrc = B8 + (size_t)(bn * 16) * 16384;

  f32x16 acc[2][4];
#pragma unroll
  for (int mi = 0; mi < 2; ++mi)
#pragma unroll
    for (int ni = 0; ni < 4; ++ni) acc[mi][ni] = (f32x16)(0.f);

  // Stage kstep t into buffer buf: A 8KB (2 issues/thread) + B 16KB (4/thread).
#define STAGE(buf, t)                                                        \
  {                                                                          \
    _Pragma("unroll")                                                        \
    for (int p = 0; p < 2; ++p) {                                            \
      const int c = p * 4 + wave;                                            \
      g2lds16(Asrc + (size_t)(t) * 8192 + c * 1024 + lane * 16,              \
              (void*)(&smem[buf][c * 1024]));                                \
    }                                                                        \
    _Pragma("unroll")                                                        \
    for (int p = 0; p < 4; ++p) {                                            \
      const int c = p * 4 + wave;                                            \
      g2lds16(Bsrc + (size_t)(t) * 16384 + c * 1024 + lane * 16,             \
              (void*)(&smem[buf][8192 + c * 1024]));                         \
    }                                                                        \
  }

#define COMPUTE(buf)                                                         \
  {                                                                          \
    const uint8_t* ap = &smem[buf][(wr * 2) * 2048] + lane * 32;             \
    const uint8_t* bp = &smem[buf][8192 + (wc * 4) * 2048] + lane * 32;      \
    i32x8 a[2], b[4];                                                        \
    _Pragma("unroll")                                                        \
    for (int mi = 0; mi < 2; ++mi) a[mi] = *(const i32x8*)(ap + mi * 2048);  \
    _Pragma("unroll")                                                        \
    for (int ni = 0; ni < 4; ++ni) b[ni] = *(const i32x8*)(bp + ni * 2048);  \
    __builtin_amdgcn_s_setprio(1);                                           \
    _Pragma("unroll")                                                        \
    for (int mi = 0; mi < 2; ++mi) {                                         \
      _Pragma("unroll")                                                      \
      for (int ni = 0; ni < 4; ++ni)                                         \
        acc[mi][ni] = __builtin_amdgcn_mfma_scale_f32_32x32x64_f8f6f4(       \
            a[mi], b[ni], acc[mi][ni], 0, 0,                                 \
            0, 0x7F7F7F7F, 0, 0x7F7F7F7F);                                   \
    }                                                                        \
    __builtin_amdgcn_s_setprio(0);                                           \
  }

  // Prologue: stage(0), stage(1); vmcnt(6) -> stage(0) landed, stage(1) flying.
  STAGE(0, 0)
  STAGE(1, 1)
  vmw<6>();
  bar();

#pragma unroll
  for (int k = 0; k < 16; ++k) {
    if (k < 14) STAGE((k + 2) % 3, k + 2)    // overwrites buf[(k-1)%3]: its
                                             // readers passed the last barrier
    COMPUTE(k % 3)
    if (k < 14) {        // ensure stage(k+1) landed; leave stage(k+2) in flight
      vmw<6>();
      bar();
    } else if (k == 14) {                    // ensure stage(15) landed
      vmw<0>();
      bar();
    }                                        // k==15: done
  }
#undef STAGE
#undef COMPUTE

  // Epilogue: 32x32 C/D layout (m101-verified): col = lane&31,
  // row = (reg&3) + 8*(reg>>2) + 4*(lane>>5). Unscale 1/16 (W was x16).
#pragma unroll
  for (int mi = 0; mi < 2; ++mi) {
#pragma unroll
    for (int r = 0; r < 16; ++r) {
      float v = 0.f;
#pragma unroll
      for (int ni = 0; ni < 4; ++ni) v += __expf(acc[mi][ni][r] * 0.0625f);
      v += __shfl_xor(v, 1);
      v += __shfl_xor(v, 2);
      v += __shfl_xor(v, 4);
      v += __shfl_xor(v, 8);
      v += __shfl_xor(v, 16);
      if ((lane & 31) == 0) {
        const int row = arow + wr * 64 + mi * 32 + (r & 3) + 8 * (r >> 2) + 4 * (lane >> 5);
        atomicAdd(&S[row], v);
      }
    }
  }
}

// ---------------- 128^2 fp32 fallback (ws too small), unchanged ----------------
__global__ __launch_bounds__(256)
void gemm_lse_fb(const float* __restrict__ Af, const float* __restrict__ Bf,
                 float* __restrict__ S) {
  __shared__ u16 As[128 * 64];
  __shared__ u16 Bs[128 * 64];

  const int tid  = threadIdx.x;
  const int lane = tid & 63;
  const int wave = tid >> 6;
  const int wr = wave >> 1, wc = wave & 1;
  const int l15 = lane & 15, l4 = lane >> 4;

  const int lid = blockIdx.x;
  const int wid = (lid & 7) * CHUNK + (lid >> 3);
  const int bm = wid & (NBM - 1);
  const int bn = wid / NBM;

  f32x4 acc[4][4];
#pragma unroll
  for (int m = 0; m < 4; ++m)
#pragma unroll
    for (int n = 0; n < 4; ++n) acc[m][n] = (f32x4)(0.f);

  for (int kt = 0; kt < DMODEL / 64; ++kt) {
    const int k0 = kt * 64;
    {
      const int row = tid >> 4;
      const int kq  = (tid & 15) * 4;
#pragma unroll
      for (int r = 0; r < 8; ++r) {
        const int rr = r * 16 + row;
        const int kd = kq ^ ((rr & 7) << 3);
        float4 a4 = *(const float4*)(Af + (size_t)(bm * 128 + rr) * DMODEL + k0 + kq);
        float4 b4 = *(const float4*)(Bf + (size_t)(bn * 128 + rr) * DMODEL + k0 + kq);
        u16x4 ap = { f2bf(a4.x), f2bf(a4.y), f2bf(a4.z), f2bf(a4.w) };
        u16x4 bp = { f2bf(b4.x), f2bf(b4.y), f2bf(b4.z), f2bf(b4.w) };
        *(u16x4*)&As[rr * 64 + kd] = ap;
        *(u16x4*)&Bs[rr * 64 + kd] = bp;
      }
    }
    __syncthreads();
#pragma unroll
    for (int kk = 0; kk < 2; ++kk) {
      bf16x8 av[4], bv[4];
      const int swz = (l15 & 7) << 3;
      const int kc  = (kk * 32 + l4 * 8) ^ swz;
#pragma unroll
      for (int m = 0; m < 4; ++m)
        av[m] = *(const bf16x8*)&As[(wr * 64 + m * 16 + l15) * 64 + kc];
#pragma unroll
      for (int n = 0; n < 4; ++n)
        bv[n] = *(const bf16x8*)&Bs[(wc * 64 + n * 16 + l15) * 64 + kc];
#pragma unroll
      for (int m = 0; m < 4; ++m)
#pragma unroll
        for (int n = 0; n < 4; ++n)
          acc[m][n] = __builtin_amdgcn_mfma_f32_16x16x32_bf16(av[m], bv[n], acc[m][n], 0, 0, 0);
    }
    __syncthreads();
  }

#pragma unroll
  for (int m = 0; m < 4; ++m) {
#pragma unroll
    for (int j = 0; j < 4; ++j) {
      float v = 0.f;
#pragma unroll
      for (int n = 0; n < 4; ++n) v += __expf(acc[m][n][j]);
      v += __shfl_xor(v, 1);
      v += __shfl_xor(v, 2);
      v += __shfl_xor(v, 4);
      v += __shfl_xor(v, 8);
      if (l15 == 0) {
        const int row = bm * 128 + wr * 64 + m * 16 + l4 * 4 + j;
        atomicAdd(&S[row], v);
      }
    }
  }
}

// ---------------- exact fp32 target score ----------------
__global__ void target_score_k(const float* __restrict__ inp, const float* __restrict__ W,
                               const int* __restrict__ tgt, float* __restrict__ ts) {
  const int gtid = blockIdx.x * blockDim.x + threadIdx.x;
  const int t = gtid >> 6;
  const int lane = threadIdx.x & 63;
  if (t >= TOKENS) return;
  bool allhi0 = true, anylo = false;
  for (int i = 0; i < 64; ++i) {
    if (tgt[2 * i + 1] != 0) allhi0 = false;
    if (tgt[2 * i] != 0) anylo = true;
  }
  const int v = (allhi0 && anylo) ? tgt[2 * t] : tgt[t];
  const float4* xr = (const float4*)(inp + (size_t)t * DMODEL);
  const float4* wr = (const float4*)(W + (size_t)v * DMODEL);
  float s = 0.f;
#pragma unroll
  for (int i = 0; i < 4; ++i) {
    float4 a = xr[lane + 64 * i];
    float4 b = wr[lane + 64 * i];
    s += a.x * b.x + a.y * b.y + a.z * b.z + a.w * b.w;
  }
#pragma unroll
  for (int off = 32; off >= 1; off >>= 1) s += __shfl_xor(s, off);
  if (lane == 0) ts[t] = s;
}

__global__ void finalize_k(const float* __restrict__ S, const float* __restrict__ ts,
                           float* __restrict__ out) {
  __shared__ float red[16];
  float s = 0.f;
  for (int t = threadIdx.x; t < TOKENS; t += blockDim.x) s += __logf(S[t]) - ts[t];
#pragma unroll
  for (int off = 32; off >= 1; off >>= 1) s += __shfl_xor(s, off);
  const int wave = threadIdx.x >> 6, lane = threadIdx.x & 63;
  if (lane == 0) red[wave] = s;
  __syncthreads();
  if (threadIdx.x == 0) {
    float tot = 0.f;
    for (int w = 0; w < (int)(blockDim.x >> 6); ++w) tot += red[w];
    out[0] = tot;
  }
}

extern "C" void kernel_launch(void* const* d_in, const int* in_sizes, int n_in,
                              void* d_out, int out_size, void* d_ws, size_t ws_size,
                              hipStream_t stream) {
  const float* inp = (const float*)d_in[0];
  const float* W   = (const float*)d_in[1];
  const int*   tgt = (const int*)d_in[2];
  float* out = (float*)d_out;

  char* ws = (char*)d_ws;
  float* S  = (float*)ws;
  float* ts = (float*)(ws + 32 * 1024);
  const size_t offA = 64 * 1024;
  const long long totalA = (long long)TOKENS * DMODEL;   // 8,388,608 bytes fp8
  const long long totalB = (long long)VOCAB * DMODEL;    // 32,768,000 bytes fp8
  const size_t offB = offA + (size_t)totalA;
  const size_t need = offB + (size_t)totalB;             // ~41.2 MB
  const bool preconv = ws_size >= need;

  hipMemsetAsync(S, 0, TOKENS * sizeof(float), stream);

  if (preconv) {
    uint8_t* A8 = (uint8_t*)(ws + offA);
    uint8_t* B8 = (uint8_t*)(ws + offB);
    convert_fp8_tiled<<<4096, 256, 0, stream>>>(inp, A8, totalA, 13, 1.0f);
    convert_fp8_tiled<<<16000, 256, 0, stream>>>(W, B8, totalB, 14, 16.0f);
    gemm_lse_fp8v6<<<NWGF, 256, 0, stream>>>(A8, B8, S);
  } else {
    gemm_lse_fb<<<NWG, 256, 0, stream>>>(inp, W, S);
  }
  target_score_k<<<(TOKENS * 64) / 256, 256, 0, stream>>>(inp, W, tgt, ts);
  finalize_k<<<1, 1024, 0, stream>>>(S, ts, out);
}

// Round 12
// 686.249 us; speedup vs baseline: 2.5258x; 1.6935x over previous
//
#include <hip/hip_runtime.h>
#include <stdint.h>

// Fused linear -> logsumexp -> NLL(sum), TOKENS x DMODEL @ (VOCAB x DMODEL)^T.
// Round 12: r11's counted-vmcnt triple-buffer schedule + r6's register profile.
//  - ROLLED loop (#pragma unroll 1), 3 explicit bodies per iteration so buffer
//    indices are compile-time but live ranges die each body. r11's only failure
//    was full 16x unroll -> 256 VGPR -> 2GB scratch (schedule itself passed).
//  - A+B triple-buffered LDS (3 x 24KB = 72KB => 2 blocks/CU). Per kstep:
//    stage(k+2) -> compute(k) -> vmcnt(6)+s_barrier. vmcnt(6) = stage(k+2)'s
//    6 loads in flight => stage(k+1) landed. Never vmcnt(0) until k=15 tail.
//  - No __launch_bounds__ min-waves (r7/r10 lesson), no persistent operand regs.
//  - Identity frag-major workspace, supertile XCD map, epilogue: r6-identical.

#define TOKENS 8192
#define DMODEL 1024
#define VOCAB  32000

// fp8 geometry: block 128x256, 4 waves (2x2), wave tile 64x128
#define NBMF   (TOKENS / 128)   // 64
#define NBNF   (VOCAB / 256)    // 125
#define NWGF   (NBMF * NBNF)    // 8000 = 8 bands x 1000

// fp32 fallback geometry
#define NBM    (TOKENS / 128)
#define NBN    (VOCAB / 128)
#define NWG    (NBM * NBN)
#define CHUNK  (NWG / 8)

typedef float  f32x4   __attribute__((ext_vector_type(4)));
typedef float  f32x16  __attribute__((ext_vector_type(16)));
typedef int    i32x8   __attribute__((ext_vector_type(8)));
typedef __bf16 bf16x8  __attribute__((ext_vector_type(8)));
typedef unsigned short u16;
typedef u16 u16x4 __attribute__((ext_vector_type(4)));

__device__ __forceinline__ u16 f2bf(float f) {
  union { float f; uint32_t u; } v; v.f = f;
  return (u16)((v.u + 0x7FFFu + ((v.u >> 16) & 1u)) >> 16);
}

// fp32 -> OCP e4m3fn, RNE, saturating.
__device__ __forceinline__ uint8_t f2e4m3(float x) {
  union { float f; uint32_t u; } v; v.f = x;
  const uint32_t s = (v.u >> 24) & 0x80u;
  const float ax = fabsf(x);
  if (ax >= 464.f) return (uint8_t)(s | 0x7E);
  if (ax < 0.015625f) {
    const int q = (int)rintf(ax * 512.f);
    return (uint8_t)(s | (uint32_t)q);
  }
  uint32_t u = v.u;
  u += 0x000FFFFFu + ((u >> 20) & 1u);
  const int E = (int)((u >> 23) & 0xFF) - 127;
  const uint32_t m3 = (u >> 20) & 0x7u;
  return (uint8_t)(s | (uint32_t)(((E + 7) << 3) | m3));
}

__device__ __forceinline__ void g2lds16(const void* gsrc, void* ldst) {
  __builtin_amdgcn_global_load_lds(
      (const __attribute__((address_space(1))) uint32_t*)(uintptr_t)gsrc,
      (__attribute__((address_space(3))) uint32_t*)(uintptr_t)ldst,
      16, 0, 0);
}

__device__ __forceinline__ void bar() {
  asm volatile("" ::: "memory");
  __builtin_amdgcn_s_barrier();
  asm volatile("" ::: "memory");
}
template <int N> __device__ __forceinline__ void vmw() {
  if constexpr (N == 6)      asm volatile("s_waitcnt vmcnt(6)" ::: "memory");
  else if constexpr (N == 0) asm volatile("s_waitcnt vmcnt(0)" ::: "memory");
}

// fp32 -> fp8, identity frag-major tiled layout.
// Tile = (row-block rb of NR=2^(log2ts-6) rows) x (kstep kt of 64 k),
// frag regions of 2048B (32 rows x 64 k). Byte x in tile:
//   sub=x>>11; l=(x&2047)>>5; row=rb*NR+sub*32+(l&31); k=kt*64+(l>>5)*32+(x&31).
__global__ void convert_fp8_tiled(const float* __restrict__ in, uint8_t* __restrict__ out,
                                  long long total, int log2ts, float scale) {
  const long long step = (long long)gridDim.x * blockDim.x * 8;
  const int NR = 1 << (log2ts - 6);
  for (long long d = ((long long)blockIdx.x * blockDim.x + threadIdx.x) * 8;
       d < total; d += step) {
    const long long tile = d >> log2ts;
    const int x   = (int)(d & ((1LL << log2ts) - 1));
    const int sub = x >> 11;
    const int rem = x & 2047;
    const int l   = rem >> 5;
    const int rb  = (int)(tile >> 4);
    const int kt  = (int)(tile & 15);
    const int row = rb * NR + sub * 32 + (l & 31);
    const int k   = kt * 64 + (l >> 5) * 32 + (rem & 31);
    const float* src = in + (size_t)row * DMODEL + k;
    const float4 f0 = *(const float4*)src;
    const float4 f1 = *(const float4*)(src + 4);
    uint8_t r[8] = { f2e4m3(f0.x * scale), f2e4m3(f0.y * scale),
                     f2e4m3(f0.z * scale), f2e4m3(f0.w * scale),
                     f2e4m3(f1.x * scale), f2e4m3(f1.y * scale),
                     f2e4m3(f1.z * scale), f2e4m3(f1.w * scale) };
    *(uint64_t*)(out + d) = *(const uint64_t*)r;
  }
}

// ---------------- MX-fp8 fused GEMM + exp-row-sum, rolled 2-deep pipeline ----------------
__global__ __launch_bounds__(256)
void gemm_lse_fp8v7(const uint8_t* __restrict__ A8, const uint8_t* __restrict__ B8,
                    float* __restrict__ S) {
  __shared__ uint8_t smem[3][24576];     // 72 KiB: per buf, A 8K | B 16K

  const int lane = threadIdx.x & 63;
  const int wave = threadIdx.x >> 6;         // 0..3
  const int wr = wave >> 1, wc = wave & 1;   // 2x2; wave tile 64x128

  // Supertile XCD map: band owns bm in [band*8, band*8+8), bn-major sweep.
  const int lid  = blockIdx.x;
  const int band = lid & 7;
  const int idx2 = lid >> 3;                 // 0..999
  const int bn   = idx2 >> 3;                // 0..124
  const int bm   = band * 8 + (idx2 & 7);    // 0..63
  const int arow = bm * 128;

  const uint8_t* Asrc = A8 + (size_t)(bm * 16) * 8192;
  const uint8_t* Bsrc = B8 + (size_t)(bn * 16) * 16384;

  f32x16 acc[2][4];
#pragma unroll
  for (int mi = 0; mi < 2; ++mi)
#pragma unroll
    for (int ni = 0; ni < 4; ++ni) acc[mi][ni] = (f32x16)(0.f);

  // Stage kstep t into buffer buf: A 8KB (2 issues/thread) + B 16KB (4/thread).
#define STAGE(buf, t)                                                        \
  {                                                                          \
    _Pragma("unroll")                                                        \
    for (int p = 0; p < 2; ++p) {                                            \
      const int c = p * 4 + wave;                                            \
      g2lds16(Asrc + (size_t)(t) * 8192 + c * 1024 + lane * 16,              \
              (void*)(&smem[buf][c * 1024]));                                \
    }                                                                        \
    _Pragma("unroll")                                                        \
    for (int p = 0; p < 4; ++p) {                                            \
      const int c = p * 4 + wave;                                            \
      g2lds16(Bsrc + (size_t)(t) * 16384 + c * 1024 + lane * 16,             \
              (void*)(&smem[buf][8192 + c * 1024]));                         \
    }                                                                        \
  }

#define COMPUTE(buf)                                                         \
  {                                                                          \
    const uint8_t* ap = &smem[buf][(wr * 2) * 2048] + lane * 32;             \
    const uint8_t* bp = &smem[buf][8192 + (wc * 4) * 2048] + lane * 32;      \
    i32x8 a[2], b[4];                                                        \
    _Pragma("unroll")                                                        \
    for (int mi = 0; mi < 2; ++mi) a[mi] = *(const i32x8*)(ap + mi * 2048);  \
    _Pragma("unroll")                                                        \
    for (int ni = 0; ni < 4; ++ni) b[ni] = *(const i32x8*)(bp + ni * 2048);  \
    __builtin_amdgcn_s_setprio(1);                                           \
    _Pragma("unroll")                                                        \
    for (int mi = 0; mi < 2; ++mi) {                                         \
      _Pragma("unroll")                                                      \
      for (int ni = 0; ni < 4; ++ni)                                         \
        acc[mi][ni] = __builtin_amdgcn_mfma_scale_f32_32x32x64_f8f6f4(       \
            a[mi], b[ni], acc[mi][ni], 0, 0,                                 \
            0, 0x7F7F7F7F, 0, 0x7F7F7F7F);                                   \
    }                                                                        \
    __builtin_amdgcn_s_setprio(0);                                           \
  }

  // Prologue: stage(0), stage(1); vmcnt(6) -> stage(0) landed, stage(1) flying.
  STAGE(0, 0)
  STAGE(1, 1)
  vmw<6>();
  bar();

  // Main loop: k = 3*tt + j (j = 0,1,2), tt = 0..4 covers k = 0..14.
  // Buffer indices are compile-time: k%3 = j; stage target (k+2)%3.
#pragma unroll 1
  for (int tt = 0; tt < 5; ++tt) {
    const int k0 = 3 * tt;
    // j = 0: compute buf0, stage(k0+2) -> buf2
    if (k0 + 2 < 16) STAGE(2, k0 + 2)
    COMPUTE(0)
    vmw<6>();
    bar();
    // j = 1: compute buf1, stage(k0+3) -> buf0
    if (k0 + 3 < 16) STAGE(0, k0 + 3)
    COMPUTE(1)
    vmw<6>();
    bar();
    // j = 2: compute buf2, stage(k0+4) -> buf1
    if (k0 + 4 < 16) STAGE(1, k0 + 4)
    COMPUTE(2)
    if (tt < 4) {
      vmw<6>();
      bar();
    }
  }
  // Tail: k = 15, buf 15%3 = 0; stage(15) was issued at k=13.
  vmw<0>();
  bar();
  COMPUTE(0)
#undef STAGE
#undef COMPUTE

  // Epilogue: 32x32 C/D layout (m101-verified): col = lane&31,
  // row = (reg&3) + 8*(reg>>2) + 4*(lane>>5). Unscale 1/16 (W was x16).
#pragma unroll
  for (int mi = 0; mi < 2; ++mi) {
#pragma unroll
    for (int r = 0; r < 16; ++r) {
      float v = 0.f;
#pragma unroll
      for (int ni = 0; ni < 4; ++ni) v += __expf(acc[mi][ni][r] * 0.0625f);
      v += __shfl_xor(v, 1);
      v += __shfl_xor(v, 2);
      v += __shfl_xor(v, 4);
      v += __shfl_xor(v, 8);
      v += __shfl_xor(v, 16);
      if ((lane & 31) == 0) {
        const int row = arow + wr * 64 + mi * 32 + (r & 3) + 8 * (r >> 2) + 4 * (lane >> 5);
        atomicAdd(&S[row], v);
      }
    }
  }
}

// ---------------- 128^2 fp32 fallback (ws too small), unchanged ----------------
__global__ __launch_bounds__(256)
void gemm_lse_fb(const float* __restrict__ Af, const float* __restrict__ Bf,
                 float* __restrict__ S) {
  __shared__ u16 As[128 * 64];
  __shared__ u16 Bs[128 * 64];

  const int tid  = threadIdx.x;
  const int lane = tid & 63;
  const int wave = tid >> 6;
  const int wr = wave >> 1, wc = wave & 1;
  const int l15 = lane & 15, l4 = lane >> 4;

  const int lid = blockIdx.x;
  const int wid = (lid & 7) * CHUNK + (lid >> 3);
  const int bm = wid & (NBM - 1);
  const int bn = wid / NBM;

  f32x4 acc[4][4];
#pragma unroll
  for (int m = 0; m < 4; ++m)
#pragma unroll
    for (int n = 0; n < 4; ++n) acc[m][n] = (f32x4)(0.f);

  for (int kt = 0; kt < DMODEL / 64; ++kt) {
    const int k0 = kt * 64;
    {
      const int row = tid >> 4;
      const int kq  = (tid & 15) * 4;
#pragma unroll
      for (int r = 0; r < 8; ++r) {
        const int rr = r * 16 + row;
        const int kd = kq ^ ((rr & 7) << 3);
        float4 a4 = *(const float4*)(Af + (size_t)(bm * 128 + rr) * DMODEL + k0 + kq);
        float4 b4 = *(const float4*)(Bf + (size_t)(bn * 128 + rr) * DMODEL + k0 + kq);
        u16x4 ap = { f2bf(a4.x), f2bf(a4.y), f2bf(a4.z), f2bf(a4.w) };
        u16x4 bp = { f2bf(b4.x), f2bf(b4.y), f2bf(b4.z), f2bf(b4.w) };
        *(u16x4*)&As[rr * 64 + kd] = ap;
        *(u16x4*)&Bs[rr * 64 + kd] = bp;
      }
    }
    __syncthreads();
#pragma unroll
    for (int kk = 0; kk < 2; ++kk) {
      bf16x8 av[4], bv[4];
      const int swz = (l15 & 7) << 3;
      const int kc  = (kk * 32 + l4 * 8) ^ swz;
#pragma unroll
      for (int m = 0; m < 4; ++m)
        av[m] = *(const bf16x8*)&As[(wr * 64 + m * 16 + l15) * 64 + kc];
#pragma unroll
      for (int n = 0; n < 4; ++n)
        bv[n] = *(const bf16x8*)&Bs[(wc * 64 + n * 16 + l15) * 64 + kc];
#pragma unroll
      for (int m = 0; m < 4; ++m)
#pragma unroll
        for (int n = 0; n < 4; ++n)
          acc[m][n] = __builtin_amdgcn_mfma_f32_16x16x32_bf16(av[m], bv[n], acc[m][n], 0, 0, 0);
    }
    __syncthreads();
  }

#pragma unroll
  for (int m = 0; m < 4; ++m) {
#pragma unroll
    for (int j = 0; j < 4; ++j) {
      float v = 0.f;
#pragma unroll
      for (int n = 0; n < 4; ++n) v += __expf(acc[m][n][j]);
      v += __shfl_xor(v, 1);
      v += __shfl_xor(v, 2);
      v += __shfl_xor(v, 4);
      v += __shfl_xor(v, 8);
      if (l15 == 0) {
        const int row = bm * 128 + wr * 64 + m * 16 + l4 * 4 + j;
        atomicAdd(&S[row], v);
      }
    }
  }
}

// ---------------- exact fp32 target score ----------------
__global__ void target_score_k(const float* __restrict__ inp, const float* __restrict__ W,
                               const int* __restrict__ tgt, float* __restrict__ ts) {
  const int gtid = blockIdx.x * blockDim.x + threadIdx.x;
  const int t = gtid >> 6;
  const int lane = threadIdx.x & 63;
  if (t >= TOKENS) return;
  bool allhi0 = true, anylo = false;
  for (int i = 0; i < 64; ++i) {
    if (tgt[2 * i + 1] != 0) allhi0 = false;
    if (tgt[2 * i] != 0) anylo = true;
  }
  const int v = (allhi0 && anylo) ? tgt[2 * t] : tgt[t];
  const float4* xr = (const float4*)(inp + (size_t)t * DMODEL);
  const float4* wr = (const float4*)(W + (size_t)v * DMODEL);
  float s = 0.f;
#pragma unroll
  for (int i = 0; i < 4; ++i) {
    float4 a = xr[lane + 64 * i];
    float4 b = wr[lane + 64 * i];
    s += a.x * b.x + a.y * b.y + a.z * b.z + a.w * b.w;
  }
#pragma unroll
  for (int off = 32; off >= 1; off >>= 1) s += __shfl_xor(s, off);
  if (lane == 0) ts[t] = s;
}

__global__ void finalize_k(const float* __restrict__ S, const float* __restrict__ ts,
                           float* __restrict__ out) {
  __shared__ float red[16];
  float s = 0.f;
  for (int t = threadIdx.x; t < TOKENS; t += blockDim.x) s += __logf(S[t]) - ts[t];
#pragma unroll
  for (int off = 32; off >= 1; off >>= 1) s += __shfl_xor(s, off);
  const int wave = threadIdx.x >> 6, lane = threadIdx.x & 63;
  if (lane == 0) red[wave] = s;
  __syncthreads();
  if (threadIdx.x == 0) {
    float tot = 0.f;
    for (int w = 0; w < (int)(blockDim.x >> 6); ++w) tot += red[w];
    out[0] = tot;
  }
}

extern "C" void kernel_launch(void* const* d_in, const int* in_sizes, int n_in,
                              void* d_out, int out_size, void* d_ws, size_t ws_size,
                              hipStream_t stream) {
  const float* inp = (const float*)d_in[0];
  const float* W   = (const float*)d_in[1];
  const int*   tgt = (const int*)d_in[2];
  float* out = (float*)d_out;

  char* ws = (char*)d_ws;
  float* S  = (float*)ws;
  float* ts = (float*)(ws + 32 * 1024);
  const size_t offA = 64 * 1024;
  const long long totalA = (long long)TOKENS * DMODEL;   // 8,388,608 bytes fp8
  const long long totalB = (long long)VOCAB * DMODEL;    // 32,768,000 bytes fp8
  const size_t offB = offA + (size_t)totalA;
  const size_t need = offB + (size_t)totalB;             // ~41.2 MB
  const bool preconv = ws_size >= need;

  hipMemsetAsync(S, 0, TOKENS * sizeof(float), stream);

  if (preconv) {
    uint8_t* A8 = (uint8_t*)(ws + offA);
    uint8_t* B8 = (uint8_t*)(ws + offB);
    convert_fp8_tiled<<<4096, 256, 0, stream>>>(inp, A8, totalA, 13, 1.0f);
    convert_fp8_tiled<<<16000, 256, 0, stream>>>(W, B8, totalB, 14, 16.0f);
    gemm_lse_fp8v7<<<NWGF, 256, 0, stream>>>(A8, B8, S);
  } else {
    gemm_lse_fb<<<NWG, 256, 0, stream>>>(inp, W, S);
  }
  target_score_k<<<(TOKENS * 64) / 256, 256, 0, stream>>>(inp, W, tgt, ts);
  finalize_k<<<1, 1024, 0, stream>>>(S, ts, out);
}